// Round 1
// baseline (307.564 us; speedup 1.0000x reference)
//
#include <hip/hip_runtime.h>
#include <hip/hip_bf16.h>

// Capsule dynamic routing, round 11.
// vs round 10 (200 us):
//  - wsum0: B operand is raw xt bf16 (uniform 1/32 folded into reduce_k
//    is_first) -> removes the 48-op/lane convert chain from the biggest pass.
//  - wsum_k: per-j K=16 MFMA (upper k-half zeroed, same pattern as logits)
//    with c applied to the f32 MFMA *output* (4 fma; output col == b so
//    c[b,n,j] is a per-lane scalar). Deletes bf2f/mul/f2bf B-prep entirely.
//  - wsum_k occupancy: 2 b-tiles/wave, grid(NCH,16) -> 8192 waves (8/SIMD).
// x[64][2048][16] f32, W[32][2048][16][16] f32 -> v[64][32][16] f32.
//
// Pipeline (carry only vsumT[n][b][d]):
//   cvt_x (j-fast, coalesced both sides)
//   pass0: wsum0_cvt (reads f32 W ONCE coalesced, converts+writes Wt[j][n][256]
//          bf16, accumulates unscaled uniform partials) -> reduce(first=1, x1/32)
//   pass1,2: LS (fused logits+softmax -> C[j][n][b] bf16), wsum, reduce
//   9 dispatches total.
//
// MFMA layouts (m89/m91/m120-verified): C/D col=lane&15, row=(lane>>4)*4+reg;
// A[m=lane&15][k=(lane>>4)*8+t]. K=32 packs 2 j per MFMA (k<16 -> j0, k>=16 -> j1)
// in wsum0; logits/wsum use single-j with k>=16 nulled via zero B half.

#define J_DIM 2048
#define NCH 128            // wsum j-chunks (16 j each)

typedef __attribute__((ext_vector_type(8))) short bf16x8;
typedef __attribute__((ext_vector_type(4))) short bf16x4;
typedef __attribute__((ext_vector_type(4))) float f32x4;

__device__ inline short f2bf(float f) {
    union { float f; unsigned u; } v; v.f = f;
    unsigned r = v.u + 0x7FFFu + ((v.u >> 16) & 1u);   // RNE
    return (short)(r >> 16);
}
__device__ inline float bf2f(short s) {
    union { unsigned u; float f; } v; v.u = ((unsigned)(unsigned short)s) << 16;
    return v.f;
}

// x[b][j][16] f32 -> xt[j][b][16] bf16. One thread per (b,j) row.
__global__ __launch_bounds__(256)
void cvt_x_t(const float* __restrict__ x, short* __restrict__ xt) {
    const int id = blockIdx.x * 256 + threadIdx.x;   // j fast for coalesced reads
    const int j = id & (J_DIM - 1), b = id >> 11;
    const float4* s = (const float4*)(x + ((size_t)b * J_DIM + j) * 16);
    float4 q0 = s[0], q1 = s[1], q2 = s[2], q3 = s[3];
    short tmp[16] = { f2bf(q0.x), f2bf(q0.y), f2bf(q0.z), f2bf(q0.w),
                      f2bf(q1.x), f2bf(q1.y), f2bf(q1.z), f2bf(q1.w),
                      f2bf(q2.x), f2bf(q2.y), f2bf(q2.z), f2bf(q2.w),
                      f2bf(q3.x), f2bf(q3.y), f2bf(q3.z), f2bf(q3.w) };
    short* d = xt + ((size_t)j * 64 + b) * 16;
    *(bf16x8*)d = *(bf16x8*)tmp;
    *(bf16x8*)(d + 8) = *(bf16x8*)&tmp[8];
}

// Pass 0: read W f32 once (coalesced 1KB-row bursts), convert, write
// Wt[j][n][256] bf16, accumulate UNSCALED uniform-c partials (1/32 applied
// in reduce_k is_first -- c is uniform so the scale is linear).
// grid(NCH, 8) x 256 thr; wave = (16-j chunk, n); 4 b-tiles in-wave.
__global__ __launch_bounds__(256)
void wsum0_cvt_k(const float* __restrict__ W, short* __restrict__ Wt,
                 const short* __restrict__ xt, short* __restrict__ sp) {
    const int t = threadIdx.x, lane = t & 63, w = t >> 6;
    const int col = lane & 15, g = lane >> 4;
    const int n = blockIdx.y * 4 + w;
    const int chunk = blockIdx.x;

    f32x4 acc[4];
#pragma unroll
    for (int bt = 0; bt < 4; ++bt) acc[bt] = (f32x4){0.f, 0.f, 0.f, 0.f};

#pragma unroll
    for (int jp = 0; jp < 8; ++jp) {
        const int jq = chunk * 16 + jp * 2 + (g >> 1);
        // lane's 8 f32 of W[n][jq] row; half-wave covers the full 1KB row
        const float4* wsrc = (const float4*)(W + ((size_t)n * J_DIM + jq) * 256 + col * 16 + (g & 1) * 8);
        float4 a = wsrc[0], b2 = wsrc[1];
        short tmp[8] = { f2bf(a.x), f2bf(a.y), f2bf(a.z), f2bf(a.w),
                         f2bf(b2.x), f2bf(b2.y), f2bf(b2.z), f2bf(b2.w) };
        bf16x8 af = *(bf16x8*)tmp;
        *(bf16x8*)(Wt + ((size_t)jq * 32 + n) * 256 + col * 16 + (g & 1) * 8) = af;
#pragma unroll
        for (int bt = 0; bt < 4; ++bt) {
            const int b = bt * 16 + col;
            bf16x8 xr = *(const bf16x8*)(xt + ((size_t)jq * 64 + b) * 16 + (g & 1) * 8);
            acc[bt] = __builtin_amdgcn_mfma_f32_16x16x32_bf16(af, xr, acc[bt], 0, 0, 0);
        }
    }
#pragma unroll
    for (int bt = 0; bt < 4; ++bt) {
        short o[4] = { f2bf(acc[bt][0]), f2bf(acc[bt][1]), f2bf(acc[bt][2]), f2bf(acc[bt][3]) };
        *(bf16x4*)(sp + (((size_t)chunk * 32 + n) * 64 + bt * 16 + col) * 16 + g * 4) = *(bf16x4*)o;
    }
}

// C[j][n][b] bf16 = softmax_n( vsumT[n,b,:] . u_hat[b,n,j,:] )
// grid(2048) x 256 thr; wave = b-tile, block = one j (16KB contiguous Wt slab).
__global__ __launch_bounds__(256)
void logits_softmax_k(const short* __restrict__ Wt, const short* __restrict__ xt,
                      const float* __restrict__ vsumT, short* __restrict__ C) {
    const int t = threadIdx.x, lane = t & 63, bt = t >> 6;
    const int col = lane & 15, g = lane >> 4;
    const int j = blockIdx.x;
    const int b = bt * 16 + col;

    bf16x8 xb = (bf16x8){0, 0, 0, 0, 0, 0, 0, 0};
    if (lane < 32)
        xb = *(const bf16x8*)(xt + ((size_t)j * 64 + b) * 16 + (g & 1) * 8);

    float logit[32];
#pragma unroll
    for (int n = 0; n < 32; ++n) {
        // A[m=col=d][k=g*8+t]; k>=16 lanes read garbage (nulled by xb=0)
        bf16x8 af = *(const bf16x8*)(Wt + ((size_t)j * 32 + n) * 256 + col * 16 + g * 8);
        f32x4 u = __builtin_amdgcn_mfma_f32_16x16x32_bf16(
            af, xb, (f32x4){0.f, 0.f, 0.f, 0.f}, 0, 0, 0);
        float4 vv = *(const float4*)(vsumT + ((size_t)n * 64 + b) * 16 + g * 4);
        float lp = vv.x * u[0] + vv.y * u[1] + vv.z * u[2] + vv.w * u[3];
        lp += __shfl_xor(lp, 16);
        lp += __shfl_xor(lp, 32);          // all lanes: logit(b, n)
        logit[n] = lp;
    }

    float mx = logit[0];
#pragma unroll
    for (int n = 1; n < 32; ++n) mx = fmaxf(mx, logit[n]);
    float Z = 0.f;
#pragma unroll
    for (int n = 0; n < 32; ++n) { logit[n] = __expf(logit[n] - mx); Z += logit[n]; }
    float rz = __builtin_amdgcn_rcpf(Z);

    if (g == 0) {
        short* row = C + (size_t)j * 32 * 64 + b;
#pragma unroll
        for (int n = 0; n < 32; ++n) row[n * 64] = f2bf(logit[n] * rz);
    }
}

// sp[chunk][n][b][d] bf16 = sum_{j in 16-chunk} c[b,n,j] * u_hat[b,n,j,d]
// Per-j K=16 MFMA (k>=16 nulled via zero B half, like logits); c applied to
// the f32 MFMA output: out col == b, so c[b,n,j] is a per-lane scalar.
// grid(NCH, 16) x 256 thr; wave = (chunk, n, b-half): 2 b-tiles, 8192 waves.
__global__ __launch_bounds__(256)
void wsum_k(const short* __restrict__ Wt, const short* __restrict__ xt,
            const short* __restrict__ C, short* __restrict__ sp) {
    const int t = threadIdx.x, lane = t & 63, w = t >> 6;
    const int col = lane & 15, g = lane >> 4;
    const int n = (blockIdx.y >> 1) * 4 + w;
    const int bh = blockIdx.y & 1;          // b-half: bt in {2bh, 2bh+1}
    const int chunk = blockIdx.x;

    f32x4 acc[2];
    acc[0] = (f32x4){0.f, 0.f, 0.f, 0.f};
    acc[1] = (f32x4){0.f, 0.f, 0.f, 0.f};

#pragma unroll
    for (int jj = 0; jj < 16; ++jj) {
        const int jq = chunk * 16 + jj;
        // A[m=col=d][k=g*8+t]; k>=16 lanes duplicate k<16 data (nulled by B=0)
        bf16x8 af = *(const bf16x8*)(Wt + ((size_t)jq * 32 + n) * 256 + col * 16 + (g & 1) * 8);
#pragma unroll
        for (int bt2 = 0; bt2 < 2; ++bt2) {
            const int b = (bh * 2 + bt2) * 16 + col;
            bf16x8 xb = (bf16x8){0, 0, 0, 0, 0, 0, 0, 0};
            if (lane < 32)
                xb = *(const bf16x8*)(xt + ((size_t)jq * 64 + b) * 16 + g * 8);
            f32x4 u = __builtin_amdgcn_mfma_f32_16x16x32_bf16(
                af, xb, (f32x4){0.f, 0.f, 0.f, 0.f}, 0, 0, 0);
            float cc = bf2f(C[((size_t)jq * 32 + n) * 64 + b]);
#pragma unroll
            for (int r = 0; r < 4; ++r) acc[bt2][r] += cc * u[r];
        }
    }
#pragma unroll
    for (int bt2 = 0; bt2 < 2; ++bt2) {
        short o[4] = { f2bf(acc[bt2][0]), f2bf(acc[bt2][1]), f2bf(acc[bt2][2]), f2bf(acc[bt2][3]) };
        *(bf16x4*)(sp + (((size_t)chunk * 32 + n) * 64 + (bh * 2 + bt2) * 16 + col) * 16 + g * 4) = *(bf16x4*)o;
    }
}

// fold NCH bf16 chunk partials, squash, update vsumT / write out. wave per (n,b).
// is_first: STORE vsum (replaces a memset dispatch) and apply the uniform-c
// 1/32 that wsum0 no longer pre-applies.
__global__ __launch_bounds__(256)
void reduce_k(const short* __restrict__ sp, float* __restrict__ vsumT,
              float* __restrict__ out, int is_first, int is_last) {
    const int t = threadIdx.x, lane = t & 63, w = t >> 6;
    const int q = blockIdx.x * 4 + w;       // 0..2047
    const int n = q >> 6, b = q & 63;
    const int d4 = lane & 3, ch = lane >> 2;   // ch 0..15

    float4 a = make_float4(0.f, 0.f, 0.f, 0.f);
#pragma unroll
    for (int m = 0; m < NCH / 16; ++m) {
        bf16x4 v = *(const bf16x4*)(sp + (((size_t)(ch + 16 * m) * 32 + n) * 64 + b) * 16 + d4 * 4);
        a.x += bf2f(v[0]); a.y += bf2f(v[1]); a.z += bf2f(v[2]); a.w += bf2f(v[3]);
    }
#pragma unroll
    for (int mk = 4; mk <= 32; mk <<= 1) {
        a.x += __shfl_xor(a.x, mk); a.y += __shfl_xor(a.y, mk);
        a.z += __shfl_xor(a.z, mk); a.w += __shfl_xor(a.w, mk);
    }
    const float sc = is_first ? 0.03125f : 1.0f;   // uniform c = 1/32 (pass 0)
    a.x *= sc; a.y *= sc; a.z *= sc; a.w *= sc;
    float tt = a.x * a.x + a.y * a.y + a.z * a.z + a.w * a.w;
    tt += __shfl_xor(tt, 1);
    tt += __shfl_xor(tt, 2);
    float s2 = tt + 1e-7f;
    float scale = sqrtf(s2) / (1.0f + s2);

    if (lane < 4) {
        float4 v = make_float4(a.x * scale, a.y * scale, a.z * scale, a.w * scale);
        if (is_last) {
            *(float4*)(out + ((size_t)b * 32 + n) * 16 + d4 * 4) = v;   // [b][n][d]
        } else {
            float* p = vsumT + ((size_t)n * 64 + b) * 16 + d4 * 4;      // [n][b][d]
            if (is_first) {
                *(float4*)p = v;
            } else {
                float4 o = *(const float4*)p;
                *(float4*)p = make_float4(o.x + v.x, o.y + v.y, o.z + v.z, o.w + v.w);
            }
        }
    }
}

extern "C" void kernel_launch(void* const* d_in, const int* in_sizes, int n_in,
                              void* d_out, int out_size, void* d_ws, size_t ws_size,
                              hipStream_t stream) {
    const float* x = (const float*)d_in[0];   // [64,2048,16]
    const float* W = (const float*)d_in[1];   // [32,2048,16,16]
    float* out = (float*)d_out;               // [64,32,16]

    char* wsb = (char*)d_ws;
    short* Wt    = (short*)(wsb);                        // 32 MB + slack
    short* xt    = (short*)(wsb + 33556480);             // 4.2 MB [j][b][16]
    short* C     = (short*)(wsb + 37750784);             // 8.4 MB [j][n][b] bf16
    short* sp    = (short*)(wsb + 46139392);             // 8.4 MB [chunk][n][b][d] bf16
    float* vsumT = (float*)(wsb + 54528000);             // 128 KB [n][b][d]

    cvt_x_t<<<512, 256, 0, stream>>>(x, xt);

    // pass 0: logits == 0 -> uniform c; W converted+transposed in-flight
    wsum0_cvt_k<<<dim3(NCH, 8), 256, 0, stream>>>(W, Wt, xt, sp);
    reduce_k<<<512, 256, 0, stream>>>(sp, vsumT, out, 1, 0);
    // pass 1
    logits_softmax_k<<<2048, 256, 0, stream>>>(Wt, xt, vsumT, C);
    wsum_k<<<dim3(NCH, 16), 256, 0, stream>>>(Wt, xt, C, sp);
    reduce_k<<<512, 256, 0, stream>>>(sp, vsumT, out, 0, 0);
    // pass 2
    logits_softmax_k<<<2048, 256, 0, stream>>>(Wt, xt, vsumT, C);
    wsum_k<<<dim3(NCH, 16), 256, 0, stream>>>(Wt, xt, C, sp);
    reduce_k<<<512, 256, 0, stream>>>(sp, vsumT, out, 0, 1);
}

// Round 2
// 194.217 us; speedup vs baseline: 1.5836x; 1.5836x over previous
//
#include <hip/hip_runtime.h>
#include <hip/hip_bf16.h>

// Capsule dynamic routing, round 12.
// Round-11 post-mortem: per-j K=16 wsum restructure was latency-bound
// (Occupancy 9%, MfmaUtil 2%, all pipes idle) -> REVERTED to round-10's
// wsum structure (K=32 2-j packing, 4 b-tiles, grid(NCH,8)).
// Kept from round 11 (validated, structure-neutral):
//  - wsum0 feeds raw xt bf16 into MFMA; uniform 1/32 folded into reduce_k.
// New in round 12:
//  - all float->bf16 packing via hardware v_cvt_pk_bf16_f32 (RNE, bit-identical
//    to the manual round): wsum B-prep 48 -> ~21 VALU ops/MFMA, wsum0 W-convert
//    32 -> 4 ops/jp, cvt_x 64 -> 8 ops, sp epilogues halved.
// x[64][2048][16] f32, W[32][2048][16][16] f32 -> v[64][32][16] f32.
//
// Pipeline (carry only vsumT[n][b][d]):
//   cvt_x (j-fast, coalesced both sides)
//   pass0: wsum0_cvt (reads f32 W ONCE coalesced, converts+writes Wt[j][n][256]
//          bf16, accumulates unscaled uniform partials) -> reduce(first=1, x1/32)
//   pass1,2: LS (fused logits+softmax -> C[j][n][b] bf16), wsum, reduce
//   9 dispatches total.
//
// MFMA layouts (m89/m91/m120-verified): C/D col=lane&15, row=(lane>>4)*4+reg;
// A[m=lane&15][k=(lane>>4)*8+t]. K=32 packs 2 j per MFMA (k<16 -> j0, k>=16 -> j1).

#define J_DIM 2048
#define NCH 128            // wsum j-chunks (16 j each)

typedef __attribute__((ext_vector_type(8))) short bf16x8;
typedef __attribute__((ext_vector_type(4))) short bf16x4;
typedef __attribute__((ext_vector_type(4))) float f32x4;

__device__ inline short f2bf(float f) {
    union { float f; unsigned u; } v; v.f = f;
    unsigned r = v.u + 0x7FFFu + ((v.u >> 16) & 1u);   // RNE
    return (short)(r >> 16);
}
__device__ inline float bf2f(short s) {
    union { unsigned u; float f; } v; v.u = ((unsigned)(unsigned short)s) << 16;
    return v.f;
}
// packed f32x2 -> bf16x2 (RNE), dst.lo = bf16(lo), dst.hi = bf16(hi)
__device__ inline int cvt_pk_bf16(float lo, float hi) {
    int r;
    asm("v_cvt_pk_bf16_f32 %0, %1, %2" : "=v"(r) : "v"(lo), "v"(hi));
    return r;
}

// x[b][j][16] f32 -> xt[j][b][16] bf16. One thread per (b,j) row.
__global__ __launch_bounds__(256)
void cvt_x_t(const float* __restrict__ x, short* __restrict__ xt) {
    const int id = blockIdx.x * 256 + threadIdx.x;   // j fast for coalesced reads
    const int j = id & (J_DIM - 1), b = id >> 11;
    const float4* s = (const float4*)(x + ((size_t)b * J_DIM + j) * 16);
    float4 q0 = s[0], q1 = s[1], q2 = s[2], q3 = s[3];
    int pk[8];
    pk[0] = cvt_pk_bf16(q0.x, q0.y); pk[1] = cvt_pk_bf16(q0.z, q0.w);
    pk[2] = cvt_pk_bf16(q1.x, q1.y); pk[3] = cvt_pk_bf16(q1.z, q1.w);
    pk[4] = cvt_pk_bf16(q2.x, q2.y); pk[5] = cvt_pk_bf16(q2.z, q2.w);
    pk[6] = cvt_pk_bf16(q3.x, q3.y); pk[7] = cvt_pk_bf16(q3.z, q3.w);
    short* d = xt + ((size_t)j * 64 + b) * 16;
    *(bf16x8*)d = *(bf16x8*)pk;
    *(bf16x8*)(d + 8) = *(bf16x8*)&pk[4];
}

// Pass 0: read W f32 once (coalesced 1KB-row bursts), convert, write
// Wt[j][n][256] bf16, accumulate UNSCALED uniform-c partials (1/32 applied
// in reduce_k is_first -- c is uniform so the scale is linear).
// grid(NCH, 8) x 256 thr; wave = (16-j chunk, n); 4 b-tiles in-wave.
__global__ __launch_bounds__(256)
void wsum0_cvt_k(const float* __restrict__ W, short* __restrict__ Wt,
                 const short* __restrict__ xt, short* __restrict__ sp) {
    const int t = threadIdx.x, lane = t & 63, w = t >> 6;
    const int col = lane & 15, g = lane >> 4;
    const int n = blockIdx.y * 4 + w;
    const int chunk = blockIdx.x;

    f32x4 acc[4];
#pragma unroll
    for (int bt = 0; bt < 4; ++bt) acc[bt] = (f32x4){0.f, 0.f, 0.f, 0.f};

#pragma unroll
    for (int jp = 0; jp < 8; ++jp) {
        const int jq = chunk * 16 + jp * 2 + (g >> 1);
        // lane's 8 f32 of W[n][jq] row; half-wave covers the full 1KB row
        const float4* wsrc = (const float4*)(W + ((size_t)n * J_DIM + jq) * 256 + col * 16 + (g & 1) * 8);
        float4 a = wsrc[0], b2 = wsrc[1];
        int pk[4];
        pk[0] = cvt_pk_bf16(a.x, a.y);   pk[1] = cvt_pk_bf16(a.z, a.w);
        pk[2] = cvt_pk_bf16(b2.x, b2.y); pk[3] = cvt_pk_bf16(b2.z, b2.w);
        bf16x8 af = *(bf16x8*)pk;
        *(bf16x8*)(Wt + ((size_t)jq * 32 + n) * 256 + col * 16 + (g & 1) * 8) = af;
#pragma unroll
        for (int bt = 0; bt < 4; ++bt) {
            const int b = bt * 16 + col;
            bf16x8 xr = *(const bf16x8*)(xt + ((size_t)jq * 64 + b) * 16 + (g & 1) * 8);
            acc[bt] = __builtin_amdgcn_mfma_f32_16x16x32_bf16(af, xr, acc[bt], 0, 0, 0);
        }
    }
#pragma unroll
    for (int bt = 0; bt < 4; ++bt) {
        int o[2] = { cvt_pk_bf16(acc[bt][0], acc[bt][1]),
                     cvt_pk_bf16(acc[bt][2], acc[bt][3]) };
        *(bf16x4*)(sp + (((size_t)chunk * 32 + n) * 64 + bt * 16 + col) * 16 + g * 4) = *(bf16x4*)o;
    }
}

// C[j][n][b] bf16 = softmax_n( vsumT[n,b,:] . u_hat[b,n,j,:] )
// grid(2048) x 256 thr; wave = b-tile, block = one j (16KB contiguous Wt slab).
__global__ __launch_bounds__(256)
void logits_softmax_k(const short* __restrict__ Wt, const short* __restrict__ xt,
                      const float* __restrict__ vsumT, short* __restrict__ C) {
    const int t = threadIdx.x, lane = t & 63, bt = t >> 6;
    const int col = lane & 15, g = lane >> 4;
    const int j = blockIdx.x;
    const int b = bt * 16 + col;

    bf16x8 xb = (bf16x8){0, 0, 0, 0, 0, 0, 0, 0};
    if (lane < 32)
        xb = *(const bf16x8*)(xt + ((size_t)j * 64 + b) * 16 + (g & 1) * 8);

    float logit[32];
#pragma unroll
    for (int n = 0; n < 32; ++n) {
        // A[m=col=d][k=g*8+t]; k>=16 lanes read garbage (nulled by xb=0)
        bf16x8 af = *(const bf16x8*)(Wt + ((size_t)j * 32 + n) * 256 + col * 16 + g * 8);
        f32x4 u = __builtin_amdgcn_mfma_f32_16x16x32_bf16(
            af, xb, (f32x4){0.f, 0.f, 0.f, 0.f}, 0, 0, 0);
        float4 vv = *(const float4*)(vsumT + ((size_t)n * 64 + b) * 16 + g * 4);
        float lp = vv.x * u[0] + vv.y * u[1] + vv.z * u[2] + vv.w * u[3];
        lp += __shfl_xor(lp, 16);
        lp += __shfl_xor(lp, 32);          // all lanes: logit(b, n)
        logit[n] = lp;
    }

    float mx = logit[0];
#pragma unroll
    for (int n = 1; n < 32; ++n) mx = fmaxf(mx, logit[n]);
    float Z = 0.f;
#pragma unroll
    for (int n = 0; n < 32; ++n) { logit[n] = __expf(logit[n] - mx); Z += logit[n]; }
    float rz = __builtin_amdgcn_rcpf(Z);

    if (g == 0) {
        short* row = C + (size_t)j * 32 * 64 + b;
#pragma unroll
        for (int n = 0; n < 32; ++n) row[n * 64] = f2bf(logit[n] * rz);
    }
}

// sp[chunk][n][b][d] bf16 = sum_{j in 16-chunk} c[b,n,j] * u_hat[b,n,j,d]
// Round-10 structure: K=32 packs 2 j; c applied on B input (per-lane scalar
// since lane's k-octet belongs to one jq), packed via v_cvt_pk_bf16_f32.
// grid(NCH, 8) x 256 thr; wave = (chunk, n); 4 b-tiles in-wave.
__global__ __launch_bounds__(256)
void wsum_k(const short* __restrict__ Wt, const short* __restrict__ xt,
            const short* __restrict__ C, short* __restrict__ sp) {
    const int t = threadIdx.x, lane = t & 63, w = t >> 6;
    const int col = lane & 15, g = lane >> 4;
    const int n = blockIdx.y * 4 + w;
    const int chunk = blockIdx.x;

    f32x4 acc[4];
#pragma unroll
    for (int bt = 0; bt < 4; ++bt) acc[bt] = (f32x4){0.f, 0.f, 0.f, 0.f};

#pragma unroll
    for (int jp = 0; jp < 8; ++jp) {
        const int jq = chunk * 16 + jp * 2 + (g >> 1);
        bf16x8 af = *(const bf16x8*)(Wt + ((size_t)jq * 32 + n) * 256 + col * 16 + (g & 1) * 8);
#pragma unroll
        for (int bt = 0; bt < 4; ++bt) {
            const int b = bt * 16 + col;
            bf16x8 xr = *(const bf16x8*)(xt + ((size_t)jq * 64 + b) * 16 + (g & 1) * 8);
            float cc = bf2f(C[((size_t)jq * 32 + n) * 64 + b]);   // 32B contiguous/wave
            int pk[4];
#pragma unroll
            for (int p = 0; p < 4; ++p)
                pk[p] = cvt_pk_bf16(cc * bf2f(xr[2 * p]), cc * bf2f(xr[2 * p + 1]));
            acc[bt] = __builtin_amdgcn_mfma_f32_16x16x32_bf16(af, *(bf16x8*)pk, acc[bt], 0, 0, 0);
        }
    }
#pragma unroll
    for (int bt = 0; bt < 4; ++bt) {
        int o[2] = { cvt_pk_bf16(acc[bt][0], acc[bt][1]),
                     cvt_pk_bf16(acc[bt][2], acc[bt][3]) };
        *(bf16x4*)(sp + (((size_t)chunk * 32 + n) * 64 + bt * 16 + col) * 16 + g * 4) = *(bf16x4*)o;
    }
}

// fold NCH bf16 chunk partials, squash, update vsumT / write out. wave per (n,b).
// is_first: STORE vsum (replaces a memset dispatch) and apply the uniform-c
// 1/32 that wsum0 no longer pre-applies.
__global__ __launch_bounds__(256)
void reduce_k(const short* __restrict__ sp, float* __restrict__ vsumT,
              float* __restrict__ out, int is_first, int is_last) {
    const int t = threadIdx.x, lane = t & 63, w = t >> 6;
    const int q = blockIdx.x * 4 + w;       // 0..2047
    const int n = q >> 6, b = q & 63;
    const int d4 = lane & 3, ch = lane >> 2;   // ch 0..15

    float4 a = make_float4(0.f, 0.f, 0.f, 0.f);
#pragma unroll
    for (int m = 0; m < NCH / 16; ++m) {
        bf16x4 v = *(const bf16x4*)(sp + (((size_t)(ch + 16 * m) * 32 + n) * 64 + b) * 16 + d4 * 4);
        a.x += bf2f(v[0]); a.y += bf2f(v[1]); a.z += bf2f(v[2]); a.w += bf2f(v[3]);
    }
#pragma unroll
    for (int mk = 4; mk <= 32; mk <<= 1) {
        a.x += __shfl_xor(a.x, mk); a.y += __shfl_xor(a.y, mk);
        a.z += __shfl_xor(a.z, mk); a.w += __shfl_xor(a.w, mk);
    }
    const float sc = is_first ? 0.03125f : 1.0f;   // uniform c = 1/32 (pass 0)
    a.x *= sc; a.y *= sc; a.z *= sc; a.w *= sc;
    float tt = a.x * a.x + a.y * a.y + a.z * a.z + a.w * a.w;
    tt += __shfl_xor(tt, 1);
    tt += __shfl_xor(tt, 2);
    float s2 = tt + 1e-7f;
    float scale = sqrtf(s2) / (1.0f + s2);

    if (lane < 4) {
        float4 v = make_float4(a.x * scale, a.y * scale, a.z * scale, a.w * scale);
        if (is_last) {
            *(float4*)(out + ((size_t)b * 32 + n) * 16 + d4 * 4) = v;   // [b][n][d]
        } else {
            float* p = vsumT + ((size_t)n * 64 + b) * 16 + d4 * 4;      // [n][b][d]
            if (is_first) {
                *(float4*)p = v;
            } else {
                float4 o = *(const float4*)p;
                *(float4*)p = make_float4(o.x + v.x, o.y + v.y, o.z + v.z, o.w + v.w);
            }
        }
    }
}

extern "C" void kernel_launch(void* const* d_in, const int* in_sizes, int n_in,
                              void* d_out, int out_size, void* d_ws, size_t ws_size,
                              hipStream_t stream) {
    const float* x = (const float*)d_in[0];   // [64,2048,16]
    const float* W = (const float*)d_in[1];   // [32,2048,16,16]
    float* out = (float*)d_out;               // [64,32,16]

    char* wsb = (char*)d_ws;
    short* Wt    = (short*)(wsb);                        // 32 MB + slack
    short* xt    = (short*)(wsb + 33556480);             // 4.2 MB [j][b][16]
    short* C     = (short*)(wsb + 37750784);             // 8.4 MB [j][n][b] bf16
    short* sp    = (short*)(wsb + 46139392);             // 8.4 MB [chunk][n][b][d] bf16
    float* vsumT = (float*)(wsb + 54528000);             // 128 KB [n][b][d]

    cvt_x_t<<<512, 256, 0, stream>>>(x, xt);

    // pass 0: logits == 0 -> uniform c; W converted+transposed in-flight
    wsum0_cvt_k<<<dim3(NCH, 8), 256, 0, stream>>>(W, Wt, xt, sp);
    reduce_k<<<512, 256, 0, stream>>>(sp, vsumT, out, 1, 0);
    // pass 1
    logits_softmax_k<<<2048, 256, 0, stream>>>(Wt, xt, vsumT, C);
    wsum_k<<<dim3(NCH, 8), 256, 0, stream>>>(Wt, xt, C, sp);
    reduce_k<<<512, 256, 0, stream>>>(sp, vsumT, out, 0, 0);
    // pass 2
    logits_softmax_k<<<2048, 256, 0, stream>>>(Wt, xt, vsumT, C);
    wsum_k<<<dim3(NCH, 8), 256, 0, stream>>>(Wt, xt, C, sp);
    reduce_k<<<512, 256, 0, stream>>>(sp, vsumT, out, 0, 1);
}

// Round 3
// 160.733 us; speedup vs baseline: 1.9135x; 1.2083x over previous
//
#include <hip/hip_runtime.h>
#include <hip/hip_bf16.h>

// Capsule dynamic routing, round 13.
// vs round 12 (194 us): logits_softmax_k + wsum_k FUSED into one kernel per
// routing pass. Rationale: the four mid dispatches (~135 us combined) sit ~3x
// above their HBM floor; logits computes u_hat via MFMA then wsum RECOMPUTES
// the same u_hat from the same Wt bytes with a bf16 C round-trip between.
// Fused kernel: block = (16-j chunk, 16-b tile), 8 waves x 4 n = all 32 n
// resident; per j: MFMA u -> logit dot -> exp -> cross-wave 1-float LDS sum
// (1 barrier, parity) -> acc += (e*rz) * u. Removes 131K wsum MFMAs, the C
// buffer entirely, and one full Wt read per pass. Softmax max-subtraction
// dropped: |v|2 <= 0.5 (squash bound), |u|2 <~ 8 => |logit| <= ~4, f32-safe,
// exact-math identical to reference. 9 -> 7 dispatches.
// Kept: cvt_x, wsum0_cvt (raw-xt B, 1/32 in reduce), reduce_k, NCH=128,
// cvt_pk_bf16 packing everywhere. Workspace offsets unchanged (C slot idle).
//
// x[64][2048][16] f32, W[32][2048][16][16] f32 -> v[64][32][16] f32.
// MFMA layouts (m89/m91/m120-verified): C/D col=lane&15, row=(lane>>4)*4+reg;
// A[m=lane&15][k=(lane>>4)*8+t]. wsum0 K=32 packs 2 j; fused uses K=16
// (upper half nulled via zero B) like old logits.

#define J_DIM 2048
#define NCH 128            // j-chunks (16 j each)

typedef __attribute__((ext_vector_type(8))) short bf16x8;
typedef __attribute__((ext_vector_type(4))) short bf16x4;
typedef __attribute__((ext_vector_type(4))) float f32x4;

__device__ inline short f2bf(float f) {
    union { float f; unsigned u; } v; v.f = f;
    unsigned r = v.u + 0x7FFFu + ((v.u >> 16) & 1u);   // RNE
    return (short)(r >> 16);
}
__device__ inline float bf2f(short s) {
    union { unsigned u; float f; } v; v.u = ((unsigned)(unsigned short)s) << 16;
    return v.f;
}
// packed f32x2 -> bf16x2 (RNE), dst.lo = bf16(lo), dst.hi = bf16(hi)
__device__ inline int cvt_pk_bf16(float lo, float hi) {
    int r;
    asm("v_cvt_pk_bf16_f32 %0, %1, %2" : "=v"(r) : "v"(lo), "v"(hi));
    return r;
}

// x[b][j][16] f32 -> xt[j][b][16] bf16. One thread per (b,j) row.
__global__ __launch_bounds__(256)
void cvt_x_t(const float* __restrict__ x, short* __restrict__ xt) {
    const int id = blockIdx.x * 256 + threadIdx.x;   // j fast for coalesced reads
    const int j = id & (J_DIM - 1), b = id >> 11;
    const float4* s = (const float4*)(x + ((size_t)b * J_DIM + j) * 16);
    float4 q0 = s[0], q1 = s[1], q2 = s[2], q3 = s[3];
    int pk[8];
    pk[0] = cvt_pk_bf16(q0.x, q0.y); pk[1] = cvt_pk_bf16(q0.z, q0.w);
    pk[2] = cvt_pk_bf16(q1.x, q1.y); pk[3] = cvt_pk_bf16(q1.z, q1.w);
    pk[4] = cvt_pk_bf16(q2.x, q2.y); pk[5] = cvt_pk_bf16(q2.z, q2.w);
    pk[6] = cvt_pk_bf16(q3.x, q3.y); pk[7] = cvt_pk_bf16(q3.z, q3.w);
    short* d = xt + ((size_t)j * 64 + b) * 16;
    *(bf16x8*)d = *(bf16x8*)pk;
    *(bf16x8*)(d + 8) = *(bf16x8*)&pk[4];
}

// Pass 0: read W f32 once (coalesced 1KB-row bursts), convert, write
// Wt[j][n][256] bf16, accumulate UNSCALED uniform-c partials (1/32 applied
// in reduce_k is_first -- c is uniform so the scale is linear).
// grid(NCH, 8) x 256 thr; wave = (16-j chunk, n); 4 b-tiles in-wave.
__global__ __launch_bounds__(256)
void wsum0_cvt_k(const float* __restrict__ W, short* __restrict__ Wt,
                 const short* __restrict__ xt, short* __restrict__ sp) {
    const int t = threadIdx.x, lane = t & 63, w = t >> 6;
    const int col = lane & 15, g = lane >> 4;
    const int n = blockIdx.y * 4 + w;
    const int chunk = blockIdx.x;

    f32x4 acc[4];
#pragma unroll
    for (int bt = 0; bt < 4; ++bt) acc[bt] = (f32x4){0.f, 0.f, 0.f, 0.f};

#pragma unroll
    for (int jp = 0; jp < 8; ++jp) {
        const int jq = chunk * 16 + jp * 2 + (g >> 1);
        // lane's 8 f32 of W[n][jq] row; half-wave covers the full 1KB row
        const float4* wsrc = (const float4*)(W + ((size_t)n * J_DIM + jq) * 256 + col * 16 + (g & 1) * 8);
        float4 a = wsrc[0], b2 = wsrc[1];
        int pk[4];
        pk[0] = cvt_pk_bf16(a.x, a.y);   pk[1] = cvt_pk_bf16(a.z, a.w);
        pk[2] = cvt_pk_bf16(b2.x, b2.y); pk[3] = cvt_pk_bf16(b2.z, b2.w);
        bf16x8 af = *(bf16x8*)pk;
        *(bf16x8*)(Wt + ((size_t)jq * 32 + n) * 256 + col * 16 + (g & 1) * 8) = af;
#pragma unroll
        for (int bt = 0; bt < 4; ++bt) {
            const int b = bt * 16 + col;
            bf16x8 xr = *(const bf16x8*)(xt + ((size_t)jq * 64 + b) * 16 + (g & 1) * 8);
            acc[bt] = __builtin_amdgcn_mfma_f32_16x16x32_bf16(af, xr, acc[bt], 0, 0, 0);
        }
    }
#pragma unroll
    for (int bt = 0; bt < 4; ++bt) {
        int o[2] = { cvt_pk_bf16(acc[bt][0], acc[bt][1]),
                     cvt_pk_bf16(acc[bt][2], acc[bt][3]) };
        *(bf16x4*)(sp + (((size_t)chunk * 32 + n) * 64 + bt * 16 + col) * 16 + g * 4) = *(bf16x4*)o;
    }
}

// Fused routing pass: sp[chunk][n][b][d] += softmax_n(v.u_hat) * u_hat for a
// 16-j chunk and one 16-b tile. grid(NCH, 4) x 512 thr (8 waves x 4 n).
// Per j per wave: 4 MFMA (u), 4 logit dots (+2 shfl each), 4 exp, 1-float
// cross-wave LDS sum (1 barrier, parity-buffered), then acc += (e*rz)*u.
__global__ __launch_bounds__(512)
void fused_pass_k(const short* __restrict__ Wt, const short* __restrict__ xt,
                  const float* __restrict__ vsumT, short* __restrict__ sp) {
    const int t = threadIdx.x, lane = t & 63, w = t >> 6;   // w 0..7: n-quad
    const int col = lane & 15, g = lane >> 4;
    const int chunk = blockIdx.x;          // 16-j chunk
    const int bt = blockIdx.y;             // b-tile 0..3
    const int b = bt * 16 + col;
    const int n0 = w * 4;

    __shared__ float psum[2][8][16];       // [parity][wave][b-col]

    // v is j-invariant: hoist the dot operands (vsumT[n][b][d], d-quad g)
    float4 vv[4];
#pragma unroll
    for (int q = 0; q < 4; ++q)
        vv[q] = *(const float4*)(vsumT + ((size_t)(n0 + q) * 64 + b) * 16 + g * 4);

    f32x4 acc[4];
#pragma unroll
    for (int q = 0; q < 4; ++q) acc[q] = (f32x4){0.f, 0.f, 0.f, 0.f};

#pragma unroll 1
    for (int jj = 0; jj < 16; ++jj) {
        const int j = chunk * 16 + jj;
        // B = x[b][j] in k<16 half; k>=16 lanes nulled (K=16 effective)
        bf16x8 xb = (bf16x8){0, 0, 0, 0, 0, 0, 0, 0};
        if (lane < 32)
            xb = *(const bf16x8*)(xt + ((size_t)j * 64 + b) * 16 + (g & 1) * 8);

        f32x4 u[4];
        float e[4];
        float ps = 0.f;
#pragma unroll
        for (int q = 0; q < 4; ++q) {
            // A[m=col=d][k=g*8+t]; k>=16 lanes read garbage (nulled by xb=0)
            bf16x8 af = *(const bf16x8*)(Wt + ((size_t)j * 32 + n0 + q) * 256 + col * 16 + g * 8);
            u[q] = __builtin_amdgcn_mfma_f32_16x16x32_bf16(
                af, xb, (f32x4){0.f, 0.f, 0.f, 0.f}, 0, 0, 0);
            float lp = vv[q].x * u[q][0] + vv[q].y * u[q][1]
                     + vv[q].z * u[q][2] + vv[q].w * u[q][3];
            lp += __shfl_xor(lp, 16);
            lp += __shfl_xor(lp, 32);      // all lanes: logit(b, n0+q)
            // no max-sub: |v|2<=0.5 (squash), |u|2<~8 => |logit|<=~4, f32-safe
            e[q] = __expf(lp);
            ps += e[q];
        }
        const int p = jj & 1;              // parity LDS buffer (WAR across j)
        if (g == 0) psum[p][w][col] = ps;
        __syncthreads();
        float Z = 0.f;
#pragma unroll
        for (int ww = 0; ww < 8; ++ww) Z += psum[p][ww][col];
        const float rz = __builtin_amdgcn_rcpf(Z);
#pragma unroll
        for (int q = 0; q < 4; ++q) {
            const float c = e[q] * rz;     // c stays f32 (no bf16 C round-trip)
#pragma unroll
            for (int r = 0; r < 4; ++r) acc[q][r] += c * u[q][r];
        }
    }

#pragma unroll
    for (int q = 0; q < 4; ++q) {
        int o[2] = { cvt_pk_bf16(acc[q][0], acc[q][1]),
                     cvt_pk_bf16(acc[q][2], acc[q][3]) };
        *(bf16x4*)(sp + (((size_t)chunk * 32 + n0 + q) * 64 + b) * 16 + g * 4) = *(bf16x4*)o;
    }
}

// fold NCH bf16 chunk partials, squash, update vsumT / write out. wave per (n,b).
// is_first: STORE vsum (replaces a memset dispatch) and apply the uniform-c
// 1/32 that wsum0 does not pre-apply.
__global__ __launch_bounds__(256)
void reduce_k(const short* __restrict__ sp, float* __restrict__ vsumT,
              float* __restrict__ out, int is_first, int is_last) {
    const int t = threadIdx.x, lane = t & 63, w = t >> 6;
    const int q = blockIdx.x * 4 + w;       // 0..2047
    const int n = q >> 6, b = q & 63;
    const int d4 = lane & 3, ch = lane >> 2;   // ch 0..15

    float4 a = make_float4(0.f, 0.f, 0.f, 0.f);
#pragma unroll
    for (int m = 0; m < NCH / 16; ++m) {
        bf16x4 v = *(const bf16x4*)(sp + (((size_t)(ch + 16 * m) * 32 + n) * 64 + b) * 16 + d4 * 4);
        a.x += bf2f(v[0]); a.y += bf2f(v[1]); a.z += bf2f(v[2]); a.w += bf2f(v[3]);
    }
#pragma unroll
    for (int mk = 4; mk <= 32; mk <<= 1) {
        a.x += __shfl_xor(a.x, mk); a.y += __shfl_xor(a.y, mk);
        a.z += __shfl_xor(a.z, mk); a.w += __shfl_xor(a.w, mk);
    }
    const float sc = is_first ? 0.03125f : 1.0f;   // uniform c = 1/32 (pass 0)
    a.x *= sc; a.y *= sc; a.z *= sc; a.w *= sc;
    float tt = a.x * a.x + a.y * a.y + a.z * a.z + a.w * a.w;
    tt += __shfl_xor(tt, 1);
    tt += __shfl_xor(tt, 2);
    float s2 = tt + 1e-7f;
    float scale = sqrtf(s2) / (1.0f + s2);

    if (lane < 4) {
        float4 v = make_float4(a.x * scale, a.y * scale, a.z * scale, a.w * scale);
        if (is_last) {
            *(float4*)(out + ((size_t)b * 32 + n) * 16 + d4 * 4) = v;   // [b][n][d]
        } else {
            float* p = vsumT + ((size_t)n * 64 + b) * 16 + d4 * 4;      // [n][b][d]
            if (is_first) {
                *(float4*)p = v;
            } else {
                float4 o = *(const float4*)p;
                *(float4*)p = make_float4(o.x + v.x, o.y + v.y, o.z + v.z, o.w + v.w);
            }
        }
    }
}

extern "C" void kernel_launch(void* const* d_in, const int* in_sizes, int n_in,
                              void* d_out, int out_size, void* d_ws, size_t ws_size,
                              hipStream_t stream) {
    const float* x = (const float*)d_in[0];   // [64,2048,16]
    const float* W = (const float*)d_in[1];   // [32,2048,16,16]
    float* out = (float*)d_out;               // [64,32,16]

    char* wsb = (char*)d_ws;
    short* Wt    = (short*)(wsb);                        // 32 MB + slack
    short* xt    = (short*)(wsb + 33556480);             // 4.2 MB [j][b][16]
    short* sp    = (short*)(wsb + 46139392);             // 8.4 MB [chunk][n][b][d] bf16
    float* vsumT = (float*)(wsb + 54528000);             // 128 KB [n][b][d]

    cvt_x_t<<<512, 256, 0, stream>>>(x, xt);

    // pass 0: logits == 0 -> uniform c; W converted+transposed in-flight
    wsum0_cvt_k<<<dim3(NCH, 8), 256, 0, stream>>>(W, Wt, xt, sp);
    reduce_k<<<512, 256, 0, stream>>>(sp, vsumT, out, 1, 0);
    // pass 1 (fused logits+softmax+wsum)
    fused_pass_k<<<dim3(NCH, 4), 512, 0, stream>>>(Wt, xt, vsumT, sp);
    reduce_k<<<512, 256, 0, stream>>>(sp, vsumT, out, 0, 0);
    // pass 2
    fused_pass_k<<<dim3(NCH, 4), 512, 0, stream>>>(Wt, xt, vsumT, sp);
    reduce_k<<<512, 256, 0, stream>>>(sp, vsumT, out, 0, 1);
}

// Round 4
// 157.486 us; speedup vs baseline: 1.9530x; 1.0206x over previous
//
#include <hip/hip_runtime.h>
#include <hip/hip_bf16.h>

// Capsule dynamic routing, round 14.
// vs round 13 (160.7 us): fused_pass_k gets a 2-stage software pipeline --
// j+1's Wt/xt loads are issued BEFORE the j-iteration's softmax barrier, so
// global-load latency (cold Wt slab ~600-900 cyc) hides under the exchange +
// MFMA chain instead of serializing in front of it. __launch_bounds__(512,4)
// pins VGPR <=128 to keep 2 blocks/CU residency (round-11 lesson).
// All other kernels identical to round 13.
//
// Pipeline (carry only vsumT[n][b][d]):
//   cvt_x; wsum0_cvt (W f32 read once, Wt bf16 written, uniform partials);
//   reduce(first); [fused logits+softmax+wsum; reduce] x2.  7 dispatches.
//
// x[64][2048][16] f32, W[32][2048][16][16] f32 -> v[64][32][16] f32.
// MFMA layouts (m89/m91/m120-verified): C/D col=lane&15, row=(lane>>4)*4+reg;
// A[m=lane&15][k=(lane>>4)*8+t]. wsum0 K=32 packs 2 j; fused uses K=16
// (upper half nulled via zero B) like old logits.

#define J_DIM 2048
#define NCH 128            // j-chunks (16 j each)

typedef __attribute__((ext_vector_type(8))) short bf16x8;
typedef __attribute__((ext_vector_type(4))) short bf16x4;
typedef __attribute__((ext_vector_type(4))) float f32x4;

__device__ inline short f2bf(float f) {
    union { float f; unsigned u; } v; v.f = f;
    unsigned r = v.u + 0x7FFFu + ((v.u >> 16) & 1u);   // RNE
    return (short)(r >> 16);
}
__device__ inline float bf2f(short s) {
    union { unsigned u; float f; } v; v.u = ((unsigned)(unsigned short)s) << 16;
    return v.f;
}
// packed f32x2 -> bf16x2 (RNE), dst.lo = bf16(lo), dst.hi = bf16(hi)
__device__ inline int cvt_pk_bf16(float lo, float hi) {
    int r;
    asm("v_cvt_pk_bf16_f32 %0, %1, %2" : "=v"(r) : "v"(lo), "v"(hi));
    return r;
}

// x[b][j][16] f32 -> xt[j][b][16] bf16. One thread per (b,j) row.
__global__ __launch_bounds__(256)
void cvt_x_t(const float* __restrict__ x, short* __restrict__ xt) {
    const int id = blockIdx.x * 256 + threadIdx.x;   // j fast for coalesced reads
    const int j = id & (J_DIM - 1), b = id >> 11;
    const float4* s = (const float4*)(x + ((size_t)b * J_DIM + j) * 16);
    float4 q0 = s[0], q1 = s[1], q2 = s[2], q3 = s[3];
    int pk[8];
    pk[0] = cvt_pk_bf16(q0.x, q0.y); pk[1] = cvt_pk_bf16(q0.z, q0.w);
    pk[2] = cvt_pk_bf16(q1.x, q1.y); pk[3] = cvt_pk_bf16(q1.z, q1.w);
    pk[4] = cvt_pk_bf16(q2.x, q2.y); pk[5] = cvt_pk_bf16(q2.z, q2.w);
    pk[6] = cvt_pk_bf16(q3.x, q3.y); pk[7] = cvt_pk_bf16(q3.z, q3.w);
    short* d = xt + ((size_t)j * 64 + b) * 16;
    *(bf16x8*)d = *(bf16x8*)pk;
    *(bf16x8*)(d + 8) = *(bf16x8*)&pk[4];
}

// Pass 0: read W f32 once (coalesced 1KB-row bursts), convert, write
// Wt[j][n][256] bf16, accumulate UNSCALED uniform-c partials (1/32 applied
// in reduce_k is_first -- c is uniform so the scale is linear).
// grid(NCH, 8) x 256 thr; wave = (16-j chunk, n); 4 b-tiles in-wave.
__global__ __launch_bounds__(256)
void wsum0_cvt_k(const float* __restrict__ W, short* __restrict__ Wt,
                 const short* __restrict__ xt, short* __restrict__ sp) {
    const int t = threadIdx.x, lane = t & 63, w = t >> 6;
    const int col = lane & 15, g = lane >> 4;
    const int n = blockIdx.y * 4 + w;
    const int chunk = blockIdx.x;

    f32x4 acc[4];
#pragma unroll
    for (int bt = 0; bt < 4; ++bt) acc[bt] = (f32x4){0.f, 0.f, 0.f, 0.f};

#pragma unroll
    for (int jp = 0; jp < 8; ++jp) {
        const int jq = chunk * 16 + jp * 2 + (g >> 1);
        // lane's 8 f32 of W[n][jq] row; half-wave covers the full 1KB row
        const float4* wsrc = (const float4*)(W + ((size_t)n * J_DIM + jq) * 256 + col * 16 + (g & 1) * 8);
        float4 a = wsrc[0], b2 = wsrc[1];
        int pk[4];
        pk[0] = cvt_pk_bf16(a.x, a.y);   pk[1] = cvt_pk_bf16(a.z, a.w);
        pk[2] = cvt_pk_bf16(b2.x, b2.y); pk[3] = cvt_pk_bf16(b2.z, b2.w);
        bf16x8 af = *(bf16x8*)pk;
        *(bf16x8*)(Wt + ((size_t)jq * 32 + n) * 256 + col * 16 + (g & 1) * 8) = af;
#pragma unroll
        for (int bt = 0; bt < 4; ++bt) {
            const int b = bt * 16 + col;
            bf16x8 xr = *(const bf16x8*)(xt + ((size_t)jq * 64 + b) * 16 + (g & 1) * 8);
            acc[bt] = __builtin_amdgcn_mfma_f32_16x16x32_bf16(af, xr, acc[bt], 0, 0, 0);
        }
    }
#pragma unroll
    for (int bt = 0; bt < 4; ++bt) {
        int o[2] = { cvt_pk_bf16(acc[bt][0], acc[bt][1]),
                     cvt_pk_bf16(acc[bt][2], acc[bt][3]) };
        *(bf16x4*)(sp + (((size_t)chunk * 32 + n) * 64 + bt * 16 + col) * 16 + g * 4) = *(bf16x4*)o;
    }
}

// Fused routing pass: sp[chunk][n][b][d] += softmax_n(v.u_hat) * u_hat for a
// 16-j chunk and one 16-b tile. grid(NCH, 4) x 512 thr (8 waves x 4 n).
// 2-stage pipeline: j+1's af/xb loads issue before j's barrier, so their
// latency hides under the softmax exchange + accumulate.
__global__ __launch_bounds__(512, 4)
void fused_pass_k(const short* __restrict__ Wt, const short* __restrict__ xt,
                  const float* __restrict__ vsumT, short* __restrict__ sp) {
    const int t = threadIdx.x, lane = t & 63, w = t >> 6;   // w 0..7: n-quad
    const int col = lane & 15, g = lane >> 4;
    const int chunk = blockIdx.x;          // 16-j chunk
    const int bt = blockIdx.y;             // b-tile 0..3
    const int b = bt * 16 + col;
    const int n0 = w * 4;

    __shared__ float psum[2][8][16];       // [parity][wave][b-col]

    // v is j-invariant: hoist the dot operands (vsumT[n][b][d], d-quad g)
    float4 vv[4];
#pragma unroll
    for (int q = 0; q < 4; ++q)
        vv[q] = *(const float4*)(vsumT + ((size_t)(n0 + q) * 64 + b) * 16 + g * 4);

    f32x4 acc[4];
#pragma unroll
    for (int q = 0; q < 4; ++q) acc[q] = (f32x4){0.f, 0.f, 0.f, 0.f};

    // prefetch stage for j = chunk*16
    const int j0 = chunk * 16;
    bf16x8 xb_n = (bf16x8){0, 0, 0, 0, 0, 0, 0, 0};
    if (lane < 32)
        xb_n = *(const bf16x8*)(xt + ((size_t)j0 * 64 + b) * 16 + (g & 1) * 8);
    bf16x8 af_n[4];
#pragma unroll
    for (int q = 0; q < 4; ++q)
        af_n[q] = *(const bf16x8*)(Wt + ((size_t)j0 * 32 + n0 + q) * 256 + col * 16 + g * 8);

#pragma unroll 1
    for (int jj = 0; jj < 16; ++jj) {
        // consume staged operands
        const bf16x8 xb = xb_n;
        bf16x8 af[4];
#pragma unroll
        for (int q = 0; q < 4; ++q) af[q] = af_n[q];

        // issue j+1 loads NOW -- in flight across the barrier below
        if (jj < 15) {
            const int jn = chunk * 16 + jj + 1;
            xb_n = (bf16x8){0, 0, 0, 0, 0, 0, 0, 0};
            if (lane < 32)
                xb_n = *(const bf16x8*)(xt + ((size_t)jn * 64 + b) * 16 + (g & 1) * 8);
#pragma unroll
            for (int q = 0; q < 4; ++q)
                af_n[q] = *(const bf16x8*)(Wt + ((size_t)jn * 32 + n0 + q) * 256 + col * 16 + g * 8);
        }

        f32x4 u[4];
        float e[4];
        float ps = 0.f;
#pragma unroll
        for (int q = 0; q < 4; ++q) {
            // A[m=col=d][k=g*8+t]; k>=16 lanes read garbage (nulled by xb=0)
            u[q] = __builtin_amdgcn_mfma_f32_16x16x32_bf16(
                af[q], xb, (f32x4){0.f, 0.f, 0.f, 0.f}, 0, 0, 0);
            float lp = vv[q].x * u[q][0] + vv[q].y * u[q][1]
                     + vv[q].z * u[q][2] + vv[q].w * u[q][3];
            lp += __shfl_xor(lp, 16);
            lp += __shfl_xor(lp, 32);      // all lanes: logit(b, n0+q)
            // no max-sub: |v|2<=0.5 (squash), |u|2<~8 => |logit|<=~4, f32-safe
            e[q] = __expf(lp);
            ps += e[q];
        }
        const int p = jj & 1;              // parity LDS buffer (WAR across j)
        if (g == 0) psum[p][w][col] = ps;
        __syncthreads();
        float Z = 0.f;
#pragma unroll
        for (int ww = 0; ww < 8; ++ww) Z += psum[p][ww][col];
        const float rz = __builtin_amdgcn_rcpf(Z);
#pragma unroll
        for (int q = 0; q < 4; ++q) {
            const float c = e[q] * rz;     // c stays f32 (no bf16 C round-trip)
#pragma unroll
            for (int r = 0; r < 4; ++r) acc[q][r] += c * u[q][r];
        }
    }

#pragma unroll
    for (int q = 0; q < 4; ++q) {
        int o[2] = { cvt_pk_bf16(acc[q][0], acc[q][1]),
                     cvt_pk_bf16(acc[q][2], acc[q][3]) };
        *(bf16x4*)(sp + (((size_t)chunk * 32 + n0 + q) * 64 + b) * 16 + g * 4) = *(bf16x4*)o;
    }
}

// fold NCH bf16 chunk partials, squash, update vsumT / write out. wave per (n,b).
// is_first: STORE vsum (replaces a memset dispatch) and apply the uniform-c
// 1/32 that wsum0 does not pre-apply.
__global__ __launch_bounds__(256)
void reduce_k(const short* __restrict__ sp, float* __restrict__ vsumT,
              float* __restrict__ out, int is_first, int is_last) {
    const int t = threadIdx.x, lane = t & 63, w = t >> 6;
    const int q = blockIdx.x * 4 + w;       // 0..2047
    const int n = q >> 6, b = q & 63;
    const int d4 = lane & 3, ch = lane >> 2;   // ch 0..15

    float4 a = make_float4(0.f, 0.f, 0.f, 0.f);
#pragma unroll
    for (int m = 0; m < NCH / 16; ++m) {
        bf16x4 v = *(const bf16x4*)(sp + (((size_t)(ch + 16 * m) * 32 + n) * 64 + b) * 16 + d4 * 4);
        a.x += bf2f(v[0]); a.y += bf2f(v[1]); a.z += bf2f(v[2]); a.w += bf2f(v[3]);
    }
#pragma unroll
    for (int mk = 4; mk <= 32; mk <<= 1) {
        a.x += __shfl_xor(a.x, mk); a.y += __shfl_xor(a.y, mk);
        a.z += __shfl_xor(a.z, mk); a.w += __shfl_xor(a.w, mk);
    }
    const float sc = is_first ? 0.03125f : 1.0f;   // uniform c = 1/32 (pass 0)
    a.x *= sc; a.y *= sc; a.z *= sc; a.w *= sc;
    float tt = a.x * a.x + a.y * a.y + a.z * a.z + a.w * a.w;
    tt += __shfl_xor(tt, 1);
    tt += __shfl_xor(tt, 2);
    float s2 = tt + 1e-7f;
    float scale = sqrtf(s2) / (1.0f + s2);

    if (lane < 4) {
        float4 v = make_float4(a.x * scale, a.y * scale, a.z * scale, a.w * scale);
        if (is_last) {
            *(float4*)(out + ((size_t)b * 32 + n) * 16 + d4 * 4) = v;   // [b][n][d]
        } else {
            float* p = vsumT + ((size_t)n * 64 + b) * 16 + d4 * 4;      // [n][b][d]
            if (is_first) {
                *(float4*)p = v;
            } else {
                float4 o = *(const float4*)p;
                *(float4*)p = make_float4(o.x + v.x, o.y + v.y, o.z + v.z, o.w + v.w);
            }
        }
    }
}

extern "C" void kernel_launch(void* const* d_in, const int* in_sizes, int n_in,
                              void* d_out, int out_size, void* d_ws, size_t ws_size,
                              hipStream_t stream) {
    const float* x = (const float*)d_in[0];   // [64,2048,16]
    const float* W = (const float*)d_in[1];   // [32,2048,16,16]
    float* out = (float*)d_out;               // [64,32,16]

    char* wsb = (char*)d_ws;
    short* Wt    = (short*)(wsb);                        // 32 MB + slack
    short* xt    = (short*)(wsb + 33556480);             // 4.2 MB [j][b][16]
    short* sp    = (short*)(wsb + 46139392);             // 8.4 MB [chunk][n][b][d] bf16
    float* vsumT = (float*)(wsb + 54528000);             // 128 KB [n][b][d]

    cvt_x_t<<<512, 256, 0, stream>>>(x, xt);

    // pass 0: logits == 0 -> uniform c; W converted+transposed in-flight
    wsum0_cvt_k<<<dim3(NCH, 8), 256, 0, stream>>>(W, Wt, xt, sp);
    reduce_k<<<512, 256, 0, stream>>>(sp, vsumT, out, 1, 0);
    // pass 1 (fused logits+softmax+wsum)
    fused_pass_k<<<dim3(NCH, 4), 512, 0, stream>>>(Wt, xt, vsumT, sp);
    reduce_k<<<512, 256, 0, stream>>>(sp, vsumT, out, 0, 0);
    // pass 2
    fused_pass_k<<<dim3(NCH, 4), 512, 0, stream>>>(Wt, xt, vsumT, sp);
    reduce_k<<<512, 256, 0, stream>>>(sp, vsumT, out, 0, 1);
}